// Round 18
// baseline (948.861 us; speedup 1.0000x reference)
//
#include <hip/hip_runtime.h>

#define SLOPE 0.2f
#define NPB 16   // nodes per block in k_zproj
#define NPB1 32  // nodes per block in k_nodeproj1

typedef float vf4 __attribute__((ext_vector_type(4)));
typedef float vf2 __attribute__((ext_vector_type(2)));
typedef _Float16 vh2 __attribute__((ext_vector_type(2)));
typedef _Float16 vh4 __attribute__((ext_vector_type(4)));
typedef _Float16 vh8 __attribute__((ext_vector_type(8)));

__device__ __forceinline__ float bcast_lane(float v, int k) {
    return __uint_as_float(__builtin_amdgcn_readlane(__float_as_uint(v), k));
}
// sum over each 16-lane row; result valid in lane 15 of each row (row_shr DPP)
__device__ __forceinline__ float dpp_sum16(float x) {
    x += __uint_as_float(__builtin_amdgcn_update_dpp(
        0, (int)__float_as_uint(x), 0x111, 0xf, 0xf, true));
    x += __uint_as_float(__builtin_amdgcn_update_dpp(
        0, (int)__float_as_uint(x), 0x112, 0xf, 0xf, true));
    x += __uint_as_float(__builtin_amdgcn_update_dpp(
        0, (int)__float_as_uint(x), 0x114, 0xf, 0xf, true));
    x += __uint_as_float(__builtin_amdgcn_update_dpp(
        0, (int)__float_as_uint(x), 0x118, 0xf, 0xf, true));
    return x;
}

// ============================ CSR build =====================================

// degree histogram + ef -> fp16 conversion (fused; conversion dominates grid)
__global__ __launch_bounds__(256) void k_deg_cvt(
    const int* __restrict__ dst, int* __restrict__ deg,
    const float* __restrict__ ef, _Float16* __restrict__ ef16, int E)
{
    const size_t i = (size_t)blockIdx.x * 256 + threadIdx.x;
    if (i < (size_t)E) atomicAdd(&deg[dst[i]], 1);
    const size_t b = i * 8;
    if (b < (size_t)E * 32) {
        const vf4 a0 = __builtin_nontemporal_load((const vf4*)(ef + b));
        const vf4 a1 = __builtin_nontemporal_load((const vf4*)(ef + b + 4));
        vh8 o;
        o[0] = (_Float16)a0.x; o[1] = (_Float16)a0.y;
        o[2] = (_Float16)a0.z; o[3] = (_Float16)a0.w;
        o[4] = (_Float16)a1.x; o[5] = (_Float16)a1.y;
        o[6] = (_Float16)a1.z; o[7] = (_Float16)a1.w;
        __builtin_nontemporal_store(o, (vh8*)(ef16 + b));
    }
}

// phase 1: per-block (1024 elements) sums
__global__ __launch_bounds__(256) void k_scan1(
    const int* __restrict__ deg, int* __restrict__ bsum, int n)
{
    const int t = threadIdx.x;
    const int i0 = blockIdx.x * 1024 + t * 4;
    int s = 0;
#pragma unroll
    for (int j = 0; j < 4; j++) if (i0 + j < n) s += deg[i0 + j];
#pragma unroll
    for (int d = 1; d < 64; d <<= 1) s += __shfl_xor(s, d, 64);
    __shared__ int ws[4];
    if ((t & 63) == 0) ws[t >> 6] = s;
    __syncthreads();
    if (t == 0) bsum[blockIdx.x] = ws[0] + ws[1] + ws[2] + ws[3];
}

// phase 2: exclusive scan of block sums (single wave), writes offs[n] = total
__global__ __launch_bounds__(64) void k_scan2(
    int* __restrict__ bsum, int* __restrict__ offs, int nb, int n)
{
    const int lane = threadIdx.x;
    int carry = 0;
    for (int base = 0; base < nb; base += 64) {
        const int i = base + lane;
        const int v = (i < nb) ? bsum[i] : 0;
        int x = v;
#pragma unroll
        for (int d = 1; d < 64; d <<= 1) {
            const int y = __shfl_up(x, d, 64);
            if (lane >= d) x += y;
        }
        if (i < nb) bsum[i] = carry + x - v;  // exclusive block base
        carry += __shfl(x, 63, 64);
    }
    if (lane == 0) offs[n] = carry;
}

// phase 3: local exclusive scan + block base -> offs, cursor
__global__ __launch_bounds__(256) void k_scan3(
    const int* __restrict__ deg, const int* __restrict__ bsum,
    int* __restrict__ offs, int* __restrict__ cursor, int n)
{
    const int t = threadIdx.x;
    const int lane = t & 63, wid = t >> 6;
    const int i0 = blockIdx.x * 1024 + t * 4;
    const int d0 = (i0     < n) ? deg[i0]     : 0;
    const int d1 = (i0 + 1 < n) ? deg[i0 + 1] : 0;
    const int d2 = (i0 + 2 < n) ? deg[i0 + 2] : 0;
    const int d3 = (i0 + 3 < n) ? deg[i0 + 3] : 0;
    const int v = d0 + d1 + d2 + d3;
    int x = v;
#pragma unroll
    for (int d = 1; d < 64; d <<= 1) {
        const int y = __shfl_up(x, d, 64);
        if (lane >= d) x += y;
    }
    __shared__ int ws[4];
    if (lane == 63) ws[wid] = x;
    __syncthreads();
    int wbase = 0;
    for (int q = 0; q < wid; q++) wbase += ws[q];
    int excl = bsum[blockIdx.x] + wbase + (x - v);
    if (i0     < n) { offs[i0]     = excl; cursor[i0]     = excl; }
    excl += d0;
    if (i0 + 1 < n) { offs[i0 + 1] = excl; cursor[i0 + 1] = excl; }
    excl += d1;
    if (i0 + 2 < n) { offs[i0 + 2] = excl; cursor[i0 + 2] = excl; }
    excl += d2;
    if (i0 + 3 < n) { offs[i0 + 3] = excl; cursor[i0 + 3] = excl; }
}

// se[p] = (src, edge_id): single 8B scattered store
__global__ __launch_bounds__(256) void k_scatter(
    const int* __restrict__ src, const int* __restrict__ dst,
    int* __restrict__ cursor, int2* __restrict__ se, int E)
{
    const int e = blockIdx.x * 256 + threadIdx.x;
    if (e >= E) return;
    const int p = atomicAdd(&cursor[dst[e]], 1);
    se[p] = make_int2(src[e], e);
}

// ======= layer-1 node projections (fp16 outputs) + fp16 copy of nf ==========
// 32 nodes/block; 8 nodes/wave -> halves per-block weight re-reads.
__global__ __launch_bounds__(256) void k_nodeproj1(
    const float* __restrict__ nf, const float* __restrict__ Wni,
    const float* __restrict__ Wnj,
    _Float16* __restrict__ fni16, _Float16* __restrict__ fnj16,
    _Float16* __restrict__ nf16, int n)
{
    __shared__ float s[128][36];
    const int t = threadIdx.x;
    const int node0 = blockIdx.x * NPB1;
#pragma unroll
    for (int i = 0; i < 4; i++) {
        const int idx = i * 256 + t;      // 0..1023
        const int nl = idx >> 5;          // 0..31
        const int k4 = (idx & 31) * 4;    // 0..124
        const int node = node0 + nl;
        vf4 v = {0.f, 0.f, 0.f, 0.f};
        if (node < n) v = *(const vf4*)(nf + (size_t)node * 128 + k4);
        s[k4][nl] = v.x; s[k4 + 1][nl] = v.y;
        s[k4 + 2][nl] = v.z; s[k4 + 3][nl] = v.w;
        if (node < n) {
            vh4 o;
            o[0] = (_Float16)v.x; o[1] = (_Float16)v.y;
            o[2] = (_Float16)v.z; o[3] = (_Float16)v.w;
            *(vh4*)(nf16 + (size_t)node * 128 + k4) = o;
        }
    }
    __syncthreads();
    const int lane = t & 63;
    const int w8 = (t >> 6) * 8;
    float ai[8] = {0, 0, 0, 0, 0, 0, 0, 0}, aj[8] = {0, 0, 0, 0, 0, 0, 0, 0};
#pragma unroll 4
    for (int k = 0; k < 128; k++) {
        const float wi = Wni[(size_t)k * 64 + lane];
        const float wj = Wnj[(size_t)k * 64 + lane];
        const float4 sv0 = *(const float4*)&s[k][w8];
        const float4 sv1 = *(const float4*)&s[k][w8 + 4];
        const float sl[8] = {sv0.x, sv0.y, sv0.z, sv0.w,
                             sv1.x, sv1.y, sv1.z, sv1.w};
#pragma unroll
        for (int nn = 0; nn < 8; nn++) {
            ai[nn] = fmaf(wi, sl[nn], ai[nn]);
            aj[nn] = fmaf(wj, sl[nn], aj[nn]);
        }
    }
#pragma unroll
    for (int nn = 0; nn < 8; nn++) {
        const int node = node0 + w8 + nn;
        if (node < n) {
            fni16[(size_t)node * 64 + lane] = (_Float16)ai[nn];
            fnj16[(size_t)node * 64 + lane] = (_Float16)aj[nn];
        }
    }
}

// ====== layer-1 fused: edge features + softmax + nf-space aggregate =========
// depth-2 software pipeline: edges it+1 and it+2 in flight during compute.
__global__ __launch_bounds__(256, 4) void k_l1(
    const int* __restrict__ offs, const int2* __restrict__ se,
    const _Float16* __restrict__ ef16,
    const _Float16* __restrict__ nf16, const _Float16* __restrict__ fni16,
    const _Float16* __restrict__ fnj16, const float* __restrict__ Wfij,
    const float* __restrict__ bedge, const float* __restrict__ attn,
    const float* __restrict__ Wfij2,
    _Float16* __restrict__ g2s, _Float16* __restrict__ zbuf, int n)
{
    const int lane = threadIdx.x & 63;
    const int node = __builtin_amdgcn_readfirstlane(blockIdx.x * 4 + (threadIdx.x >> 6));
    if (node >= n) return;
    const int beg = offs[node], end = offs[node + 1];
    const float fjb = (float)fnj16[(size_t)node * 64 + lane] + bedge[lane];
    const float at = attn[lane];
    const float w2f = Wfij2[(lane & 15) * 4 + (lane >> 4)];
    // packed fp16 weight pairs: wf[j] = (Wfij[2j][lane], Wfij[2j+1][lane])
    vh2 wf[16];
#pragma unroll
    for (int j = 0; j < 16; j++) {
        vh2 p;
        p.x = (_Float16)Wfij[(2 * j) * 64 + lane];
        p.y = (_Float16)Wfij[(2 * j + 1) * 64 + lane];
        wf[j] = p;
    }
#pragma unroll
    for (int j = 0; j < 16; j++) asm volatile("" : "+v"(wf[j]));

    float s0 = 0.f, s1 = 0.f, s2 = 0.f, s3 = 0.f;
    vf2 z0 = {0.f, 0.f}, z1 = {0.f, 0.f}, z2 = {0.f, 0.f}, z3 = {0.f, 0.f};

#define PAIR(u, j) (vh2){(u)[2 * (j)], (u)[2 * (j) + 1]}
#define LOADE(ss, which) {                                                     \
    const int sp_ = __builtin_amdgcn_readlane(spv, (which));                   \
    const int ed_ = __builtin_amdgcn_readlane(edv, (which));                   \
    const vh8* __restrict__ er_ =                                              \
        (const vh8*)(ef16 + ((size_t)(unsigned)ed_ << 5));                     \
    ss##u0 = __builtin_nontemporal_load(er_ + 0);                              \
    ss##u1 = __builtin_nontemporal_load(er_ + 1);                              \
    ss##u2 = __builtin_nontemporal_load(er_ + 2);                              \
    ss##u3 = __builtin_nontemporal_load(er_ + 3);                              \
    ss##fni = (float)fni16[(size_t)(unsigned)sp_ * 64 + lane];                 \
    ss##nv = *(const vh2*)(nf16 + (size_t)(unsigned)sp_ * 128 + lane * 2); }

    for (int base = beg; base < end; base += 64) {
        const int rem = end - base;
        const int cnt = (rem < 64) ? rem : 64;
        const int idx = base + ((lane < cnt) ? lane : (cnt - 1));
        const int2 sev = se[idx];
        const int spv = sev.x, edv = sev.y;
        // 3 rotating stages A (compute), B (arrived/in-flight), C (issued)
        vh8 Au0, Au1, Au2, Au3; float Afni; vh2 Anv;
        vh8 Bu0, Bu1, Bu2, Bu3; float Bfni; vh2 Bnv;
        vh8 Cu0, Cu1, Cu2, Cu3; float Cfni; vh2 Cnv;
        LOADE(A, 0)
        LOADE(B, (1 < cnt) ? 1 : 0)
        for (int it = 0; it < cnt; ++it) {
            const int itn = (it + 2 < cnt) ? (it + 2) : (cnt - 1);
            LOADE(C, itn)
            // ---- compute stage A (pure-register)
            float f0 = Afni + fjb;
            f0 = __builtin_amdgcn_fdot2(PAIR(Au0, 0), wf[0],  f0, false);
            f0 = __builtin_amdgcn_fdot2(PAIR(Au0, 1), wf[1],  f0, false);
            f0 = __builtin_amdgcn_fdot2(PAIR(Au0, 2), wf[2],  f0, false);
            f0 = __builtin_amdgcn_fdot2(PAIR(Au0, 3), wf[3],  f0, false);
            float f1 = __builtin_amdgcn_fdot2(PAIR(Au1, 0), wf[4], 0.f, false);
            f1 = __builtin_amdgcn_fdot2(PAIR(Au1, 1), wf[5],  f1, false);
            f1 = __builtin_amdgcn_fdot2(PAIR(Au1, 2), wf[6],  f1, false);
            f1 = __builtin_amdgcn_fdot2(PAIR(Au1, 3), wf[7],  f1, false);
            float f2 = __builtin_amdgcn_fdot2(PAIR(Au2, 0), wf[8], 0.f, false);
            f2 = __builtin_amdgcn_fdot2(PAIR(Au2, 1), wf[9],  f2, false);
            f2 = __builtin_amdgcn_fdot2(PAIR(Au2, 2), wf[10], f2, false);
            f2 = __builtin_amdgcn_fdot2(PAIR(Au2, 3), wf[11], f2, false);
            float f3 = __builtin_amdgcn_fdot2(PAIR(Au3, 0), wf[12], 0.f, false);
            f3 = __builtin_amdgcn_fdot2(PAIR(Au3, 1), wf[13], f3, false);
            f3 = __builtin_amdgcn_fdot2(PAIR(Au3, 2), wf[14], f3, false);
            f3 = __builtin_amdgcn_fdot2(PAIR(Au3, 3), wf[15], f3, false);
            const float f = (f0 + f1) + (f2 + f3);
            const float fl = (f > 0.f) ? f : SLOPE * f;
            float r = fmaxf(fl, 0.f);
            r += __shfl_xor(r, 16, 64);
            r += __shfl_xor(r, 32, 64);
            float g = dpp_sum16(0.25f * r * w2f);
            if ((lane & 15) == 15)
                g2s[(size_t)(base + it) * 4 + (lane >> 4)] = (_Float16)g;
            const float t = dpp_sum16(fl * at);
            const float ce = __expf(t);
            const float c0 = bcast_lane(ce, 15);
            const float c1 = bcast_lane(ce, 31);
            const float c2 = bcast_lane(ce, 47);
            const float c3 = bcast_lane(ce, 63);
            const float nvx = (float)Anv.x, nvy = (float)Anv.y;
            s0 += c0; s1 += c1; s2 += c2; s3 += c3;
            z0.x = fmaf(c0, nvx, z0.x); z0.y = fmaf(c0, nvy, z0.y);
            z1.x = fmaf(c1, nvx, z1.x); z1.y = fmaf(c1, nvy, z1.y);
            z2.x = fmaf(c2, nvx, z2.x); z2.y = fmaf(c2, nvy, z2.y);
            z3.x = fmaf(c3, nvx, z3.x); z3.y = fmaf(c3, nvy, z3.y);
            // rotate pipeline stages
            Au0 = Bu0; Au1 = Bu1; Au2 = Bu2; Au3 = Bu3; Afni = Bfni; Anv = Bnv;
            Bu0 = Cu0; Bu1 = Cu1; Bu2 = Cu2; Bu3 = Cu3; Bfni = Cfni; Bnv = Cnv;
        }
    }
#undef LOADE
#undef PAIR
    const float i0 = (s0 > 0.f) ? 1.f / s0 : 0.f;
    const float i1 = (s1 > 0.f) ? 1.f / s1 : 0.f;
    const float i2 = (s2 > 0.f) ? 1.f / s2 : 0.f;
    const float i3 = (s3 > 0.f) ? 1.f / s3 : 0.f;
    _Float16* zb = zbuf + (size_t)node * 512;
    vh2 o;
    o.x = (_Float16)(z0.x * i0); o.y = (_Float16)(z0.y * i0);
    *(vh2*)(zb + 0   + lane * 2) = o;
    o.x = (_Float16)(z1.x * i1); o.y = (_Float16)(z1.y * i1);
    *(vh2*)(zb + 128 + lane * 2) = o;
    o.x = (_Float16)(z2.x * i2); o.y = (_Float16)(z2.y * i2);
    *(vh2*)(zb + 256 + lane * 2) = o;
    o.x = (_Float16)(z3.x * i3); o.y = (_Float16)(z3.y * i3);
    *(vh2*)(zb + 384 + lane * 2) = o;
}

// ====== z-space -> hbuf projection: hbuf = 0.25*sum_h relu(z_h@Wnode_h + b_h)
__global__ __launch_bounds__(256) void k_zproj(
    const _Float16* __restrict__ zbuf, const int* __restrict__ offs,
    const float* __restrict__ Wnode, const float* __restrict__ bnode,
    _Float16* __restrict__ hbuf16, int n)
{
    __shared__ float s[512][20];
    const int t = threadIdx.x;
    const int node0 = blockIdx.x * NPB;
#pragma unroll
    for (int i = 0; i < 8; i++) {
        const int idx = i * 256 + t;        // 0..2047
        const int nl = idx >> 7;            // 0..15
        const int kk = (idx & 127) * 4;     // 0..508
        const int node = node0 + nl;
        vh4 v = {0.f, 0.f, 0.f, 0.f};
        if (node < n) v = *(const vh4*)(zbuf + (size_t)node * 512 + kk);
        s[kk][nl]     = (float)v[0];
        s[kk + 1][nl] = (float)v[1];
        s[kk + 2][nl] = (float)v[2];
        s[kk + 3][nl] = (float)v[3];
    }
    __syncthreads();
    const int lane = t & 63;
    const int w4 = (t >> 6) * 4;
    bool zf[4];
    float hb[4] = {0, 0, 0, 0};
#pragma unroll
    for (int nn = 0; nn < 4; nn++) {
        const int node = node0 + w4 + nn;
        zf[nn] = (node < n) && (offs[node] < offs[node + 1]);
    }
#pragma unroll
    for (int h = 0; h < 4; h++) {
        float acc[4];
        const float bv = bnode[h * 64 + lane];
#pragma unroll
        for (int nn = 0; nn < 4; nn++) acc[nn] = zf[nn] ? bv : 0.f;
#pragma unroll 4
        for (int k = 0; k < 128; k++) {
            const float wv = Wnode[(size_t)k * 256 + h * 64 + lane];
            const float4 sv = *(const float4*)&s[h * 128 + k][w4];
            acc[0] = fmaf(wv, sv.x, acc[0]);
            acc[1] = fmaf(wv, sv.y, acc[1]);
            acc[2] = fmaf(wv, sv.z, acc[2]);
            acc[3] = fmaf(wv, sv.w, acc[3]);
        }
#pragma unroll
        for (int nn = 0; nn < 4; nn++) hb[nn] += fmaxf(acc[nn], 0.f);
    }
#pragma unroll
    for (int nn = 0; nn < 4; nn++) {
        const int node = node0 + w4 + nn;
        if (node < n) hbuf16[(size_t)node * 64 + lane] = (_Float16)(0.25f * hb[nn]);
    }
}

// ======================= layer-2 node projections ===========================
__global__ __launch_bounds__(256) void k_nodeproj2(
    const _Float16* __restrict__ hbuf16, const float* __restrict__ Wni,
    const float* __restrict__ Wnj, const float* __restrict__ Wnode,
    const float* __restrict__ bnode,
    float* __restrict__ fni2, float* __restrict__ fnj2,
    _Float16* __restrict__ ft2h, int n)
{
    __shared__ float sh[4][64];
    const int lane = threadIdx.x & 63, w = threadIdx.x >> 6;
    const int node = blockIdx.x * 4 + w;
    const int nc = (node < n) ? node : (n - 1);
    const float v = (float)hbuf16[(size_t)nc * 64 + lane];
    sh[w][lane] = v;
    __syncthreads();
    float acc = bnode[lane];
#pragma unroll 4
    for (int k = 0; k < 64; k++) acc = fmaf(sh[w][k], Wnode[k * 64 + lane], acc);
    float pi[4], pj[4];
#pragma unroll
    for (int h = 0; h < 4; h++) { pi[h] = v * Wni[lane * 4 + h]; pj[h] = v * Wnj[lane * 4 + h]; }
#pragma unroll
    for (int mk = 1; mk < 64; mk <<= 1) {
#pragma unroll
        for (int h = 0; h < 4; h++) {
            pi[h] += __shfl_xor(pi[h], mk, 64);
            pj[h] += __shfl_xor(pj[h], mk, 64);
        }
    }
    if (node < n) {
        ft2h[(size_t)node * 64 + lane] = (_Float16)acc;
        if (lane == 0) {
            *(float4*)(fni2 + (size_t)node * 4) = make_float4(pi[0], pi[1], pi[2], pi[3]);
            *(float4*)(fnj2 + (size_t)node * 4) = make_float4(pj[0], pj[1], pj[2], pj[3]);
        }
    }
}

// ====== layer-2 fused: edge logits + softmax + message passing ==============
// depth-2 software pipeline.
__global__ __launch_bounds__(256) void k_l2(
    const int* __restrict__ offs, const int2* __restrict__ se,
    const _Float16* __restrict__ g2s, const float* __restrict__ fni2,
    const float* __restrict__ fnj2, const _Float16* __restrict__ ft2h,
    const float* __restrict__ bedge2, const float* __restrict__ attn2,
    float* __restrict__ out, int n)
{
    const int lane = threadIdx.x & 63;
    const int node = __builtin_amdgcn_readfirstlane(blockIdx.x * 4 + (threadIdx.x >> 6));
    if (node >= n) return;
    const int beg = offs[node], end = offs[node + 1];
    const int h = lane >> 4;
    const float base_ = fnj2[(size_t)node * 4 + h] + bedge2[h];
    const float at = attn2[h];
    float s = 0.f, acc = 0.f;
#define LOADE2(ss, which) {                                                    \
    const int sp_ = __builtin_amdgcn_readlane(spv, (which));                   \
    ss##gq = *(const vh4*)(g2s + (size_t)(base + (which)) * 4);                \
    ss##fq = *(const float4*)(fni2 + (size_t)(unsigned)sp_ * 4);               \
    ss##ftv = (float)ft2h[(size_t)(unsigned)sp_ * 64 + lane]; }
    for (int base = beg; base < end; base += 64) {
        const int rem = end - base;
        const int cnt = (rem < 64) ? rem : 64;
        const int idx = base + ((lane < cnt) ? lane : (cnt - 1));
        const int spv = se[idx].x;
        vh4 Agq; float4 Afq; float Aftv;
        vh4 Bgq; float4 Bfq; float Bftv;
        vh4 Cgq; float4 Cfq; float Cftv;
        LOADE2(A, 0)
        LOADE2(B, (1 < cnt) ? 1 : 0)
        for (int it = 0; it < cnt; ++it) {
            const int itn = (it + 2 < cnt) ? (it + 2) : (cnt - 1);
            LOADE2(C, itn)
            // compute stage A
            const float gh = (float)((h == 0) ? Agq.x : (h == 1) ? Agq.y : (h == 2) ? Agq.z : Agq.w);
            const float fh = (h == 0) ? Afq.x : (h == 1) ? Afq.y : (h == 2) ? Afq.z : Afq.w;
            const float f = base_ + fh + gh;
            const float fl = (f > 0.f) ? f : SLOPE * f;
            const float c = __expf(fl * at);
            s += c;
            acc = fmaf(c, Aftv, acc);
            // rotate
            Agq = Bgq; Afq = Bfq; Aftv = Bftv;
            Bgq = Cgq; Bfq = Cfq; Bftv = Cftv;
        }
    }
#undef LOADE2
    out[(size_t)node * 64 + lane] = (s > 0.f) ? acc / s : 0.f;
}

extern "C" void kernel_launch(void* const* d_in, const int* in_sizes, int n_in,
                              void* d_out, int out_size, void* d_ws, size_t ws_size,
                              hipStream_t stream)
{
    const float* nfeat  = (const float*)d_in[0];
    const float* efeat  = (const float*)d_in[1];
    const int*   src    = (const int*)d_in[2];
    const int*   dst    = (const int*)d_in[3];
    const float* W1ni   = (const float*)d_in[4];
    const float* W1fij  = (const float*)d_in[5];
    const float* W1nj   = (const float*)d_in[6];
    const float* b1e    = (const float*)d_in[7];
    const float* W1node = (const float*)d_in[8];
    const float* b1n    = (const float*)d_in[9];
    const float* attn1  = (const float*)d_in[10];
    const float* W2ni   = (const float*)d_in[11];
    const float* W2fij  = (const float*)d_in[12];
    const float* W2nj   = (const float*)d_in[13];
    const float* b2e    = (const float*)d_in[14];
    const float* W2node = (const float*)d_in[15];
    const float* b2n    = (const float*)d_in[16];
    const float* attn2  = (const float*)d_in[17];
    const int n = in_sizes[0] / 128;
    const int E = in_sizes[2];
    float* out = (float*)d_out;

    char* w = (char*)d_ws;
    auto alloc = [&](size_t bytes) {
        char* p = w; w += (bytes + 255) & ~(size_t)255; return p;
    };
    _Float16* ef16  = (_Float16*)alloc((size_t)E * 32 * 2);
    _Float16* zbuf  = (_Float16*)alloc((size_t)n * 512 * 2);
    _Float16* g2s   = (_Float16*)alloc((size_t)E * 4 * 2);
    _Float16* fni16 = (_Float16*)alloc((size_t)n * 64 * 2);
    _Float16* fnj16 = (_Float16*)alloc((size_t)n * 64 * 2);
    _Float16* nf16  = (_Float16*)alloc((size_t)n * 128 * 2);
    _Float16* ft2h  = (_Float16*)alloc((size_t)n * 64 * 2);
    _Float16* hbuf16= (_Float16*)alloc((size_t)n * 64 * 2);
    int*      deg   = (int*)alloc((size_t)n * 4);
    int*      offs  = (int*)alloc((size_t)(n + 1) * 4);
    int*      curs  = (int*)alloc((size_t)n * 4);
    int2*     se    = (int2*)alloc((size_t)E * 8);
    float*    fni2  = (float*)alloc((size_t)n * 4 * 4);
    float*    fnj2  = (float*)alloc((size_t)n * 4 * 4);
    const int nb = (n + 1023) / 1024;
    int*      bsum  = (int*)alloc((size_t)nb * 4);

    // ---- CSR build (parallel scan) + ef fp16 conversion
    hipMemsetAsync(deg, 0, (size_t)n * 4, stream);
    const int cvtBlocks = (int)(((size_t)E * 4 + 255) / 256);
    k_deg_cvt<<<cvtBlocks, 256, 0, stream>>>(dst, deg, efeat, ef16, E);
    k_scan1<<<nb, 256, 0, stream>>>(deg, bsum, n);
    k_scan2<<<1, 64, 0, stream>>>(bsum, offs, nb, n);
    k_scan3<<<nb, 256, 0, stream>>>(deg, bsum, offs, curs, n);
    k_scatter<<<(E + 255) / 256, 256, 0, stream>>>(src, dst, curs, se, E);

    // ---- layer 1
    k_nodeproj1<<<(n + NPB1 - 1) / NPB1, 256, 0, stream>>>(
        nfeat, W1ni, W1nj, fni16, fnj16, nf16, n);
    k_l1<<<(n + 3) / 4, 256, 0, stream>>>(offs, se, ef16, nf16,
                                          fni16, fnj16, W1fij, b1e, attn1,
                                          W2fij, g2s, zbuf, n);
    k_zproj<<<(n + NPB - 1) / NPB, 256, 0, stream>>>(zbuf, offs, W1node, b1n,
                                                     hbuf16, n);
    // ---- layer 2
    k_nodeproj2<<<(n + 3) / 4, 256, 0, stream>>>(hbuf16, W2ni, W2nj, W2node, b2n,
                                                 fni2, fnj2, ft2h, n);
    k_l2<<<(n + 3) / 4, 256, 0, stream>>>(offs, se, g2s, fni2, fnj2, ft2h,
                                          b2e, attn2, out, n);
}

// Round 19
// 889.072 us; speedup vs baseline: 1.0672x; 1.0672x over previous
//
#include <hip/hip_runtime.h>

#define SLOPE 0.2f
#define NPB 16   // nodes per block in k_zproj
#define NPB1 32  // nodes per block in k_nodeproj1

typedef float vf4 __attribute__((ext_vector_type(4)));
typedef float vf2 __attribute__((ext_vector_type(2)));
typedef _Float16 vh2 __attribute__((ext_vector_type(2)));
typedef _Float16 vh4 __attribute__((ext_vector_type(4)));
typedef _Float16 vh8 __attribute__((ext_vector_type(8)));

__device__ __forceinline__ float bcast_lane(float v, int k) {
    return __uint_as_float(__builtin_amdgcn_readlane(__float_as_uint(v), k));
}
// sum over each 16-lane row; result valid in lane 15 of each row (row_shr DPP)
__device__ __forceinline__ float dpp_sum16(float x) {
    x += __uint_as_float(__builtin_amdgcn_update_dpp(
        0, (int)__float_as_uint(x), 0x111, 0xf, 0xf, true));
    x += __uint_as_float(__builtin_amdgcn_update_dpp(
        0, (int)__float_as_uint(x), 0x112, 0xf, 0xf, true));
    x += __uint_as_float(__builtin_amdgcn_update_dpp(
        0, (int)__float_as_uint(x), 0x114, 0xf, 0xf, true));
    x += __uint_as_float(__builtin_amdgcn_update_dpp(
        0, (int)__float_as_uint(x), 0x118, 0xf, 0xf, true));
    return x;
}

// ============================ CSR build =====================================

// degree histogram + ef -> fp16 conversion (fused; conversion dominates grid)
__global__ __launch_bounds__(256) void k_deg_cvt(
    const int* __restrict__ dst, int* __restrict__ deg,
    const float* __restrict__ ef, _Float16* __restrict__ ef16, int E)
{
    const size_t i = (size_t)blockIdx.x * 256 + threadIdx.x;
    if (i < (size_t)E) atomicAdd(&deg[dst[i]], 1);
    const size_t b = i * 8;
    if (b < (size_t)E * 32) {
        const vf4 a0 = __builtin_nontemporal_load((const vf4*)(ef + b));
        const vf4 a1 = __builtin_nontemporal_load((const vf4*)(ef + b + 4));
        vh8 o;
        o[0] = (_Float16)a0.x; o[1] = (_Float16)a0.y;
        o[2] = (_Float16)a0.z; o[3] = (_Float16)a0.w;
        o[4] = (_Float16)a1.x; o[5] = (_Float16)a1.y;
        o[6] = (_Float16)a1.z; o[7] = (_Float16)a1.w;
        __builtin_nontemporal_store(o, (vh8*)(ef16 + b));
    }
}

// phase 1: per-block (1024 elements) sums
__global__ __launch_bounds__(256) void k_scan1(
    const int* __restrict__ deg, int* __restrict__ bsum, int n)
{
    const int t = threadIdx.x;
    const int i0 = blockIdx.x * 1024 + t * 4;
    int s = 0;
#pragma unroll
    for (int j = 0; j < 4; j++) if (i0 + j < n) s += deg[i0 + j];
#pragma unroll
    for (int d = 1; d < 64; d <<= 1) s += __shfl_xor(s, d, 64);
    __shared__ int ws[4];
    if ((t & 63) == 0) ws[t >> 6] = s;
    __syncthreads();
    if (t == 0) bsum[blockIdx.x] = ws[0] + ws[1] + ws[2] + ws[3];
}

// phase 2: exclusive scan of block sums (single wave), writes offs[n] = total
__global__ __launch_bounds__(64) void k_scan2(
    int* __restrict__ bsum, int* __restrict__ offs, int nb, int n)
{
    const int lane = threadIdx.x;
    int carry = 0;
    for (int base = 0; base < nb; base += 64) {
        const int i = base + lane;
        const int v = (i < nb) ? bsum[i] : 0;
        int x = v;
#pragma unroll
        for (int d = 1; d < 64; d <<= 1) {
            const int y = __shfl_up(x, d, 64);
            if (lane >= d) x += y;
        }
        if (i < nb) bsum[i] = carry + x - v;  // exclusive block base
        carry += __shfl(x, 63, 64);
    }
    if (lane == 0) offs[n] = carry;
}

// phase 3: local exclusive scan + block base -> offs, cursor
__global__ __launch_bounds__(256) void k_scan3(
    const int* __restrict__ deg, const int* __restrict__ bsum,
    int* __restrict__ offs, int* __restrict__ cursor, int n)
{
    const int t = threadIdx.x;
    const int lane = t & 63, wid = t >> 6;
    const int i0 = blockIdx.x * 1024 + t * 4;
    const int d0 = (i0     < n) ? deg[i0]     : 0;
    const int d1 = (i0 + 1 < n) ? deg[i0 + 1] : 0;
    const int d2 = (i0 + 2 < n) ? deg[i0 + 2] : 0;
    const int d3 = (i0 + 3 < n) ? deg[i0 + 3] : 0;
    const int v = d0 + d1 + d2 + d3;
    int x = v;
#pragma unroll
    for (int d = 1; d < 64; d <<= 1) {
        const int y = __shfl_up(x, d, 64);
        if (lane >= d) x += y;
    }
    __shared__ int ws[4];
    if (lane == 63) ws[wid] = x;
    __syncthreads();
    int wbase = 0;
    for (int q = 0; q < wid; q++) wbase += ws[q];
    int excl = bsum[blockIdx.x] + wbase + (x - v);
    if (i0     < n) { offs[i0]     = excl; cursor[i0]     = excl; }
    excl += d0;
    if (i0 + 1 < n) { offs[i0 + 1] = excl; cursor[i0 + 1] = excl; }
    excl += d1;
    if (i0 + 2 < n) { offs[i0 + 2] = excl; cursor[i0 + 2] = excl; }
    excl += d2;
    if (i0 + 3 < n) { offs[i0 + 3] = excl; cursor[i0 + 3] = excl; }
}

// se[p] = (src, edge_id): single 8B scattered store
__global__ __launch_bounds__(256) void k_scatter(
    const int* __restrict__ src, const int* __restrict__ dst,
    int* __restrict__ cursor, int2* __restrict__ se, int E)
{
    const int e = blockIdx.x * 256 + threadIdx.x;
    if (e >= E) return;
    const int p = atomicAdd(&cursor[dst[e]], 1);
    se[p] = make_int2(src[e], e);
}

// ======= layer-1 node projections (fp16 outputs) + fp16 copy of nf ==========
// 32 nodes/block; 8 nodes/wave -> halves per-block weight re-reads.
__global__ __launch_bounds__(256) void k_nodeproj1(
    const float* __restrict__ nf, const float* __restrict__ Wni,
    const float* __restrict__ Wnj,
    _Float16* __restrict__ fni16, _Float16* __restrict__ fnj16,
    _Float16* __restrict__ nf16, int n)
{
    __shared__ float s[128][36];
    const int t = threadIdx.x;
    const int node0 = blockIdx.x * NPB1;
#pragma unroll
    for (int i = 0; i < 4; i++) {
        const int idx = i * 256 + t;      // 0..1023
        const int nl = idx >> 5;          // 0..31
        const int k4 = (idx & 31) * 4;    // 0..124
        const int node = node0 + nl;
        vf4 v = {0.f, 0.f, 0.f, 0.f};
        if (node < n) v = *(const vf4*)(nf + (size_t)node * 128 + k4);
        s[k4][nl] = v.x; s[k4 + 1][nl] = v.y;
        s[k4 + 2][nl] = v.z; s[k4 + 3][nl] = v.w;
        if (node < n) {
            vh4 o;
            o[0] = (_Float16)v.x; o[1] = (_Float16)v.y;
            o[2] = (_Float16)v.z; o[3] = (_Float16)v.w;
            *(vh4*)(nf16 + (size_t)node * 128 + k4) = o;
        }
    }
    __syncthreads();
    const int lane = t & 63;
    const int w8 = (t >> 6) * 8;
    float ai[8] = {0, 0, 0, 0, 0, 0, 0, 0}, aj[8] = {0, 0, 0, 0, 0, 0, 0, 0};
#pragma unroll 4
    for (int k = 0; k < 128; k++) {
        const float wi = Wni[(size_t)k * 64 + lane];
        const float wj = Wnj[(size_t)k * 64 + lane];
        const float4 sv0 = *(const float4*)&s[k][w8];
        const float4 sv1 = *(const float4*)&s[k][w8 + 4];
        const float sl[8] = {sv0.x, sv0.y, sv0.z, sv0.w,
                             sv1.x, sv1.y, sv1.z, sv1.w};
#pragma unroll
        for (int nn = 0; nn < 8; nn++) {
            ai[nn] = fmaf(wi, sl[nn], ai[nn]);
            aj[nn] = fmaf(wj, sl[nn], aj[nn]);
        }
    }
#pragma unroll
    for (int nn = 0; nn < 8; nn++) {
        const int node = node0 + w8 + nn;
        if (node < n) {
            fni16[(size_t)node * 64 + lane] = (_Float16)ai[nn];
            fnj16[(size_t)node * 64 + lane] = (_Float16)aj[nn];
        }
    }
}

// ====== layer-1 fused: edge features + softmax + nf-space aggregate =========
// depth-1 software pipeline (R17 proven best).
__global__ __launch_bounds__(256, 4) void k_l1(
    const int* __restrict__ offs, const int2* __restrict__ se,
    const _Float16* __restrict__ ef16,
    const _Float16* __restrict__ nf16, const _Float16* __restrict__ fni16,
    const _Float16* __restrict__ fnj16, const float* __restrict__ Wfij,
    const float* __restrict__ bedge, const float* __restrict__ attn,
    const float* __restrict__ Wfij2,
    _Float16* __restrict__ g2s, _Float16* __restrict__ zbuf, int n)
{
    const int lane = threadIdx.x & 63;
    const int node = __builtin_amdgcn_readfirstlane(blockIdx.x * 4 + (threadIdx.x >> 6));
    if (node >= n) return;
    const int beg = offs[node], end = offs[node + 1];
    const float fjb = (float)fnj16[(size_t)node * 64 + lane] + bedge[lane];
    const float at = attn[lane];
    const float w2f = Wfij2[(lane & 15) * 4 + (lane >> 4)];
    // packed fp16 weight pairs: wf[j] = (Wfij[2j][lane], Wfij[2j+1][lane])
    vh2 wf[16];
#pragma unroll
    for (int j = 0; j < 16; j++) {
        vh2 p;
        p.x = (_Float16)Wfij[(2 * j) * 64 + lane];
        p.y = (_Float16)Wfij[(2 * j + 1) * 64 + lane];
        wf[j] = p;
    }
#pragma unroll
    for (int j = 0; j < 16; j++) asm volatile("" : "+v"(wf[j]));

    float s0 = 0.f, s1 = 0.f, s2 = 0.f, s3 = 0.f;
    vf2 z0 = {0.f, 0.f}, z1 = {0.f, 0.f}, z2 = {0.f, 0.f}, z3 = {0.f, 0.f};

#define PAIR(u, j) (vh2){(u)[2 * (j)], (u)[2 * (j) + 1]}
    for (int base = beg; base < end; base += 64) {
        const int rem = end - base;
        const int cnt = (rem < 64) ? rem : 64;
        const int idx = base + ((lane < cnt) ? lane : (cnt - 1));
        const int2 sev = se[idx];
        const int spv = sev.x, edv = sev.y;
        // prologue: load edge 0
        {
            const int sp0 = __builtin_amdgcn_readlane(spv, 0);
            const int ed0 = __builtin_amdgcn_readlane(edv, 0);
            const vh8* __restrict__ er0 =
                (const vh8*)(ef16 + ((size_t)(unsigned)ed0 << 5));
            vh8 u0 = __builtin_nontemporal_load(er0 + 0);
            vh8 u1 = __builtin_nontemporal_load(er0 + 1);
            vh8 u2 = __builtin_nontemporal_load(er0 + 2);
            vh8 u3 = __builtin_nontemporal_load(er0 + 3);
            float fniv = (float)fni16[(size_t)(unsigned)sp0 * 64 + lane];
            vh2 nvh = *(const vh2*)(nf16 + (size_t)(unsigned)sp0 * 128 + lane * 2);
            for (int it = 0; it < cnt; ++it) {
                // issue next edge's gathers (prefetch)
                const int itn = (it + 1 < cnt) ? (it + 1) : it;
                const int spn = __builtin_amdgcn_readlane(spv, itn);
                const int edn = __builtin_amdgcn_readlane(edv, itn);
                const vh8* __restrict__ ern =
                    (const vh8*)(ef16 + ((size_t)(unsigned)edn << 5));
                const vh8 w0 = __builtin_nontemporal_load(ern + 0);
                const vh8 w1 = __builtin_nontemporal_load(ern + 1);
                const vh8 w2 = __builtin_nontemporal_load(ern + 2);
                const vh8 w3 = __builtin_nontemporal_load(ern + 3);
                const float fnin = (float)fni16[(size_t)(unsigned)spn * 64 + lane];
                const vh2 nvhn = *(const vh2*)(nf16 + (size_t)(unsigned)spn * 128 + lane * 2);
                // ---- compute current edge (pure-register)
                float f0 = fniv + fjb;
                f0 = __builtin_amdgcn_fdot2(PAIR(u0, 0), wf[0],  f0, false);
                f0 = __builtin_amdgcn_fdot2(PAIR(u0, 1), wf[1],  f0, false);
                f0 = __builtin_amdgcn_fdot2(PAIR(u0, 2), wf[2],  f0, false);
                f0 = __builtin_amdgcn_fdot2(PAIR(u0, 3), wf[3],  f0, false);
                float f1 = __builtin_amdgcn_fdot2(PAIR(u1, 0), wf[4], 0.f, false);
                f1 = __builtin_amdgcn_fdot2(PAIR(u1, 1), wf[5],  f1, false);
                f1 = __builtin_amdgcn_fdot2(PAIR(u1, 2), wf[6],  f1, false);
                f1 = __builtin_amdgcn_fdot2(PAIR(u1, 3), wf[7],  f1, false);
                float f2 = __builtin_amdgcn_fdot2(PAIR(u2, 0), wf[8], 0.f, false);
                f2 = __builtin_amdgcn_fdot2(PAIR(u2, 1), wf[9],  f2, false);
                f2 = __builtin_amdgcn_fdot2(PAIR(u2, 2), wf[10], f2, false);
                f2 = __builtin_amdgcn_fdot2(PAIR(u2, 3), wf[11], f2, false);
                float f3 = __builtin_amdgcn_fdot2(PAIR(u3, 0), wf[12], 0.f, false);
                f3 = __builtin_amdgcn_fdot2(PAIR(u3, 1), wf[13], f3, false);
                f3 = __builtin_amdgcn_fdot2(PAIR(u3, 2), wf[14], f3, false);
                f3 = __builtin_amdgcn_fdot2(PAIR(u3, 3), wf[15], f3, false);
                const float f = (f0 + f1) + (f2 + f3);
                const float fl = (f > 0.f) ? f : SLOPE * f;
                float r = fmaxf(fl, 0.f);
                r += __shfl_xor(r, 16, 64);
                r += __shfl_xor(r, 32, 64);
                float g = dpp_sum16(0.25f * r * w2f);
                if ((lane & 15) == 15)
                    g2s[(size_t)(base + it) * 4 + (lane >> 4)] = (_Float16)g;
                const float t = dpp_sum16(fl * at);
                const float ce = __expf(t);
                const float c0 = bcast_lane(ce, 15);
                const float c1 = bcast_lane(ce, 31);
                const float c2 = bcast_lane(ce, 47);
                const float c3 = bcast_lane(ce, 63);
                const float nvx = (float)nvh.x, nvy = (float)nvh.y;
                s0 += c0; s1 += c1; s2 += c2; s3 += c3;
                z0.x = fmaf(c0, nvx, z0.x); z0.y = fmaf(c0, nvy, z0.y);
                z1.x = fmaf(c1, nvx, z1.x); z1.y = fmaf(c1, nvy, z1.y);
                z2.x = fmaf(c2, nvx, z2.x); z2.y = fmaf(c2, nvy, z2.y);
                z3.x = fmaf(c3, nvx, z3.x); z3.y = fmaf(c3, nvy, z3.y);
                // rotate pipeline registers
                u0 = w0; u1 = w1; u2 = w2; u3 = w3;
                fniv = fnin; nvh = nvhn;
            }
        }
    }
#undef PAIR
    const float i0 = (s0 > 0.f) ? 1.f / s0 : 0.f;
    const float i1 = (s1 > 0.f) ? 1.f / s1 : 0.f;
    const float i2 = (s2 > 0.f) ? 1.f / s2 : 0.f;
    const float i3 = (s3 > 0.f) ? 1.f / s3 : 0.f;
    _Float16* zb = zbuf + (size_t)node * 512;
    vh2 o;
    o.x = (_Float16)(z0.x * i0); o.y = (_Float16)(z0.y * i0);
    *(vh2*)(zb + 0   + lane * 2) = o;
    o.x = (_Float16)(z1.x * i1); o.y = (_Float16)(z1.y * i1);
    *(vh2*)(zb + 128 + lane * 2) = o;
    o.x = (_Float16)(z2.x * i2); o.y = (_Float16)(z2.y * i2);
    *(vh2*)(zb + 256 + lane * 2) = o;
    o.x = (_Float16)(z3.x * i3); o.y = (_Float16)(z3.y * i3);
    *(vh2*)(zb + 384 + lane * 2) = o;
}

// ====== z-space -> hbuf projection via packed fp16 dot2 =====================
// hbuf = 0.25*sum_h relu(z_h@Wnode_h + b_h); LDS holds z as vh2 k-pairs.
__global__ __launch_bounds__(256) void k_zproj(
    const _Float16* __restrict__ zbuf, const int* __restrict__ offs,
    const float* __restrict__ Wnode, const float* __restrict__ bnode,
    _Float16* __restrict__ hbuf16, int n)
{
    __shared__ vh2 s2[256][20];  // [k-pair][node], rows 80B (16B-aligned)
    const int t = threadIdx.x;
    const int node0 = blockIdx.x * NPB;
#pragma unroll
    for (int i = 0; i < 8; i++) {
        const int idx = i * 256 + t;        // 0..2047
        const int nl = idx >> 7;            // 0..15
        const int q4 = idx & 127;           // 4-half chunk 0..127
        const int node = node0 + nl;
        vh4 v = {0.f, 0.f, 0.f, 0.f};
        if (node < n) v = *(const vh4*)(zbuf + (size_t)node * 512 + q4 * 4);
        vh2 p0; p0.x = v[0]; p0.y = v[1];
        vh2 p1; p1.x = v[2]; p1.y = v[3];
        s2[q4 * 2][nl]     = p0;
        s2[q4 * 2 + 1][nl] = p1;
    }
    __syncthreads();
    const int lane = t & 63;
    const int w4 = (t >> 6) * 4;
    bool zf[4];
    float hb[4] = {0, 0, 0, 0};
#pragma unroll
    for (int nn = 0; nn < 4; nn++) {
        const int node = node0 + w4 + nn;
        zf[nn] = (node < n) && (offs[node] < offs[node + 1]);
    }
#pragma unroll
    for (int h = 0; h < 4; h++) {
        float acc[4];
        const float bv = bnode[h * 64 + lane];
#pragma unroll
        for (int nn = 0; nn < 4; nn++) acc[nn] = zf[nn] ? bv : 0.f;
#pragma unroll 2
        for (int kp = 0; kp < 64; kp++) {
            const float w0 = Wnode[(size_t)(2 * kp) * 256 + h * 64 + lane];
            const float w1 = Wnode[(size_t)(2 * kp + 1) * 256 + h * 64 + lane];
            vh2 wp; wp.x = (_Float16)w0; wp.y = (_Float16)w1;
            // 4 node-pairs, one 16B broadcast LDS read
            const vh8 zv = *(const vh8*)&s2[h * 64 + kp][w4];
            vh2 a;
            a.x = zv[0]; a.y = zv[1];
            acc[0] = __builtin_amdgcn_fdot2(a, wp, acc[0], false);
            a.x = zv[2]; a.y = zv[3];
            acc[1] = __builtin_amdgcn_fdot2(a, wp, acc[1], false);
            a.x = zv[4]; a.y = zv[5];
            acc[2] = __builtin_amdgcn_fdot2(a, wp, acc[2], false);
            a.x = zv[6]; a.y = zv[7];
            acc[3] = __builtin_amdgcn_fdot2(a, wp, acc[3], false);
        }
#pragma unroll
        for (int nn = 0; nn < 4; nn++) hb[nn] += fmaxf(acc[nn], 0.f);
    }
#pragma unroll
    for (int nn = 0; nn < 4; nn++) {
        const int node = node0 + w4 + nn;
        if (node < n) hbuf16[(size_t)node * 64 + lane] = (_Float16)(0.25f * hb[nn]);
    }
}

// ======================= layer-2 node projections ===========================
__global__ __launch_bounds__(256) void k_nodeproj2(
    const _Float16* __restrict__ hbuf16, const float* __restrict__ Wni,
    const float* __restrict__ Wnj, const float* __restrict__ Wnode,
    const float* __restrict__ bnode,
    float* __restrict__ fni2, float* __restrict__ fnj2,
    _Float16* __restrict__ ft2h, int n)
{
    __shared__ float sh[4][64];
    const int lane = threadIdx.x & 63, w = threadIdx.x >> 6;
    const int node = blockIdx.x * 4 + w;
    const int nc = (node < n) ? node : (n - 1);
    const float v = (float)hbuf16[(size_t)nc * 64 + lane];
    sh[w][lane] = v;
    __syncthreads();
    float acc = bnode[lane];
#pragma unroll 4
    for (int k = 0; k < 64; k++) acc = fmaf(sh[w][k], Wnode[k * 64 + lane], acc);
    float pi[4], pj[4];
#pragma unroll
    for (int h = 0; h < 4; h++) { pi[h] = v * Wni[lane * 4 + h]; pj[h] = v * Wnj[lane * 4 + h]; }
#pragma unroll
    for (int mk = 1; mk < 64; mk <<= 1) {
#pragma unroll
        for (int h = 0; h < 4; h++) {
            pi[h] += __shfl_xor(pi[h], mk, 64);
            pj[h] += __shfl_xor(pj[h], mk, 64);
        }
    }
    if (node < n) {
        ft2h[(size_t)node * 64 + lane] = (_Float16)acc;
        if (lane == 0) {
            *(float4*)(fni2 + (size_t)node * 4) = make_float4(pi[0], pi[1], pi[2], pi[3]);
            *(float4*)(fnj2 + (size_t)node * 4) = make_float4(pj[0], pj[1], pj[2], pj[3]);
        }
    }
}

// ====== layer-2 fused: edge logits + softmax + message passing ==============
// depth-1 software pipeline (R17 proven best).
__global__ __launch_bounds__(256) void k_l2(
    const int* __restrict__ offs, const int2* __restrict__ se,
    const _Float16* __restrict__ g2s, const float* __restrict__ fni2,
    const float* __restrict__ fnj2, const _Float16* __restrict__ ft2h,
    const float* __restrict__ bedge2, const float* __restrict__ attn2,
    float* __restrict__ out, int n)
{
    const int lane = threadIdx.x & 63;
    const int node = __builtin_amdgcn_readfirstlane(blockIdx.x * 4 + (threadIdx.x >> 6));
    if (node >= n) return;
    const int beg = offs[node], end = offs[node + 1];
    const int h = lane >> 4;
    const float base_ = fnj2[(size_t)node * 4 + h] + bedge2[h];
    const float at = attn2[h];
    float s = 0.f, acc = 0.f;
    for (int base = beg; base < end; base += 64) {
        const int rem = end - base;
        const int cnt = (rem < 64) ? rem : 64;
        const int idx = base + ((lane < cnt) ? lane : (cnt - 1));
        const int spv = se[idx].x;
        // prologue: edge 0
        const int sp0 = __builtin_amdgcn_readlane(spv, 0);
        vh4 gq = *(const vh4*)(g2s + (size_t)base * 4);
        float4 fq = *(const float4*)(fni2 + (size_t)(unsigned)sp0 * 4);
        float ftv = (float)ft2h[(size_t)(unsigned)sp0 * 64 + lane];
        for (int it = 0; it < cnt; ++it) {
            const int itn = (it + 1 < cnt) ? (it + 1) : it;
            const int spn = __builtin_amdgcn_readlane(spv, itn);
            const vh4 gqn = *(const vh4*)(g2s + (size_t)(base + itn) * 4);
            const float4 fqn = *(const float4*)(fni2 + (size_t)(unsigned)spn * 4);
            const float ftvn = (float)ft2h[(size_t)(unsigned)spn * 64 + lane];
            // compute current
            const float gh = (float)((h == 0) ? gq.x : (h == 1) ? gq.y : (h == 2) ? gq.z : gq.w);
            const float fh = (h == 0) ? fq.x : (h == 1) ? fq.y : (h == 2) ? fq.z : fq.w;
            const float f = base_ + fh + gh;
            const float fl = (f > 0.f) ? f : SLOPE * f;
            const float c = __expf(fl * at);
            s += c;
            acc = fmaf(c, ftv, acc);
            // rotate
            gq = gqn; fq = fqn; ftv = ftvn;
        }
    }
    out[(size_t)node * 64 + lane] = (s > 0.f) ? acc / s : 0.f;
}

extern "C" void kernel_launch(void* const* d_in, const int* in_sizes, int n_in,
                              void* d_out, int out_size, void* d_ws, size_t ws_size,
                              hipStream_t stream)
{
    const float* nfeat  = (const float*)d_in[0];
    const float* efeat  = (const float*)d_in[1];
    const int*   src    = (const int*)d_in[2];
    const int*   dst    = (const int*)d_in[3];
    const float* W1ni   = (const float*)d_in[4];
    const float* W1fij  = (const float*)d_in[5];
    const float* W1nj   = (const float*)d_in[6];
    const float* b1e    = (const float*)d_in[7];
    const float* W1node = (const float*)d_in[8];
    const float* b1n    = (const float*)d_in[9];
    const float* attn1  = (const float*)d_in[10];
    const float* W2ni   = (const float*)d_in[11];
    const float* W2fij  = (const float*)d_in[12];
    const float* W2nj   = (const float*)d_in[13];
    const float* b2e    = (const float*)d_in[14];
    const float* W2node = (const float*)d_in[15];
    const float* b2n    = (const float*)d_in[16];
    const float* attn2  = (const float*)d_in[17];
    const int n = in_sizes[0] / 128;
    const int E = in_sizes[2];
    float* out = (float*)d_out;

    char* w = (char*)d_ws;
    auto alloc = [&](size_t bytes) {
        char* p = w; w += (bytes + 255) & ~(size_t)255; return p;
    };
    _Float16* ef16  = (_Float16*)alloc((size_t)E * 32 * 2);
    _Float16* zbuf  = (_Float16*)alloc((size_t)n * 512 * 2);
    _Float16* g2s   = (_Float16*)alloc((size_t)E * 4 * 2);
    _Float16* fni16 = (_Float16*)alloc((size_t)n * 64 * 2);
    _Float16* fnj16 = (_Float16*)alloc((size_t)n * 64 * 2);
    _Float16* nf16  = (_Float16*)alloc((size_t)n * 128 * 2);
    _Float16* ft2h  = (_Float16*)alloc((size_t)n * 64 * 2);
    _Float16* hbuf16= (_Float16*)alloc((size_t)n * 64 * 2);
    int*      deg   = (int*)alloc((size_t)n * 4);
    int*      offs  = (int*)alloc((size_t)(n + 1) * 4);
    int*      curs  = (int*)alloc((size_t)n * 4);
    int2*     se    = (int2*)alloc((size_t)E * 8);
    float*    fni2  = (float*)alloc((size_t)n * 4 * 4);
    float*    fnj2  = (float*)alloc((size_t)n * 4 * 4);
    const int nb = (n + 1023) / 1024;
    int*      bsum  = (int*)alloc((size_t)nb * 4);

    // ---- CSR build (parallel scan) + ef fp16 conversion
    hipMemsetAsync(deg, 0, (size_t)n * 4, stream);
    const int cvtBlocks = (int)(((size_t)E * 4 + 255) / 256);
    k_deg_cvt<<<cvtBlocks, 256, 0, stream>>>(dst, deg, efeat, ef16, E);
    k_scan1<<<nb, 256, 0, stream>>>(deg, bsum, n);
    k_scan2<<<1, 64, 0, stream>>>(bsum, offs, nb, n);
    k_scan3<<<nb, 256, 0, stream>>>(deg, bsum, offs, curs, n);
    k_scatter<<<(E + 255) / 256, 256, 0, stream>>>(src, dst, curs, se, E);

    // ---- layer 1
    k_nodeproj1<<<(n + NPB1 - 1) / NPB1, 256, 0, stream>>>(
        nfeat, W1ni, W1nj, fni16, fnj16, nf16, n);
    k_l1<<<(n + 3) / 4, 256, 0, stream>>>(offs, se, ef16, nf16,
                                          fni16, fnj16, W1fij, b1e, attn1,
                                          W2fij, g2s, zbuf, n);
    k_zproj<<<(n + NPB - 1) / NPB, 256, 0, stream>>>(zbuf, offs, W1node, b1n,
                                                     hbuf16, n);
    // ---- layer 2
    k_nodeproj2<<<(n + 3) / 4, 256, 0, stream>>>(hbuf16, W2ni, W2nj, W2node, b2n,
                                                 fni2, fnj2, ft2h, n);
    k_l2<<<(n + 3) / 4, 256, 0, stream>>>(offs, se, g2s, fni2, fnj2, ft2h,
                                          b2e, attn2, out, n);
}

// Round 21
// 888.181 us; speedup vs baseline: 1.0683x; 1.0010x over previous
//
#include <hip/hip_runtime.h>

#define SLOPE 0.2f
#define NPB 16   // nodes per block in k_zproj
#define NPB1 32  // nodes per block in k_nodeproj1

typedef float vf4 __attribute__((ext_vector_type(4)));
typedef float vf2 __attribute__((ext_vector_type(2)));
typedef _Float16 vh2 __attribute__((ext_vector_type(2)));
typedef _Float16 vh4 __attribute__((ext_vector_type(4)));
typedef _Float16 vh8 __attribute__((ext_vector_type(8)));

__device__ __forceinline__ float bcast_lane(float v, int k) {
    return __uint_as_float(__builtin_amdgcn_readlane(__float_as_uint(v), k));
}
// sum over each 16-lane row; result valid in lane 15 of each row (row_shr DPP)
__device__ __forceinline__ float dpp_sum16(float x) {
    x += __uint_as_float(__builtin_amdgcn_update_dpp(
        0, (int)__float_as_uint(x), 0x111, 0xf, 0xf, true));
    x += __uint_as_float(__builtin_amdgcn_update_dpp(
        0, (int)__float_as_uint(x), 0x112, 0xf, 0xf, true));
    x += __uint_as_float(__builtin_amdgcn_update_dpp(
        0, (int)__float_as_uint(x), 0x114, 0xf, 0xf, true));
    x += __uint_as_float(__builtin_amdgcn_update_dpp(
        0, (int)__float_as_uint(x), 0x118, 0xf, 0xf, true));
    return x;
}
// packed-fp16 variant: sums both halves over each 16-lane row (lane 15 valid)
__device__ __forceinline__ vh2 dpp_sum16_pk(vh2 x) {
    int xb, yb;
    vh2 y;
    __builtin_memcpy(&xb, &x, 4);
    yb = __builtin_amdgcn_update_dpp(0, xb, 0x111, 0xf, 0xf, true);
    __builtin_memcpy(&y, &yb, 4);
    x = x + y;
    __builtin_memcpy(&xb, &x, 4);
    yb = __builtin_amdgcn_update_dpp(0, xb, 0x112, 0xf, 0xf, true);
    __builtin_memcpy(&y, &yb, 4);
    x = x + y;
    __builtin_memcpy(&xb, &x, 4);
    yb = __builtin_amdgcn_update_dpp(0, xb, 0x114, 0xf, 0xf, true);
    __builtin_memcpy(&y, &yb, 4);
    x = x + y;
    __builtin_memcpy(&xb, &x, 4);
    yb = __builtin_amdgcn_update_dpp(0, xb, 0x118, 0xf, 0xf, true);
    __builtin_memcpy(&y, &yb, 4);
    x = x + y;
    return x;
}

// ============================ CSR build =====================================

// degree histogram + ef -> fp16 conversion (fused; conversion dominates grid)
__global__ __launch_bounds__(256) void k_deg_cvt(
    const int* __restrict__ dst, int* __restrict__ deg,
    const float* __restrict__ ef, _Float16* __restrict__ ef16, int E)
{
    const size_t i = (size_t)blockIdx.x * 256 + threadIdx.x;
    if (i < (size_t)E) atomicAdd(&deg[dst[i]], 1);
    const size_t b = i * 8;
    if (b < (size_t)E * 32) {
        const vf4 a0 = __builtin_nontemporal_load((const vf4*)(ef + b));
        const vf4 a1 = __builtin_nontemporal_load((const vf4*)(ef + b + 4));
        vh8 o;
        o[0] = (_Float16)a0.x; o[1] = (_Float16)a0.y;
        o[2] = (_Float16)a0.z; o[3] = (_Float16)a0.w;
        o[4] = (_Float16)a1.x; o[5] = (_Float16)a1.y;
        o[6] = (_Float16)a1.z; o[7] = (_Float16)a1.w;
        __builtin_nontemporal_store(o, (vh8*)(ef16 + b));
    }
}

// phase 1: per-block (1024 elements) sums
__global__ __launch_bounds__(256) void k_scan1(
    const int* __restrict__ deg, int* __restrict__ bsum, int n)
{
    const int t = threadIdx.x;
    const int i0 = blockIdx.x * 1024 + t * 4;
    int s = 0;
#pragma unroll
    for (int j = 0; j < 4; j++) if (i0 + j < n) s += deg[i0 + j];
#pragma unroll
    for (int d = 1; d < 64; d <<= 1) s += __shfl_xor(s, d, 64);
    __shared__ int ws[4];
    if ((t & 63) == 0) ws[t >> 6] = s;
    __syncthreads();
    if (t == 0) bsum[blockIdx.x] = ws[0] + ws[1] + ws[2] + ws[3];
}

// phase 2: exclusive scan of block sums (single wave), writes offs[n] = total
__global__ __launch_bounds__(64) void k_scan2(
    int* __restrict__ bsum, int* __restrict__ offs, int nb, int n)
{
    const int lane = threadIdx.x;
    int carry = 0;
    for (int base = 0; base < nb; base += 64) {
        const int i = base + lane;
        const int v = (i < nb) ? bsum[i] : 0;
        int x = v;
#pragma unroll
        for (int d = 1; d < 64; d <<= 1) {
            const int y = __shfl_up(x, d, 64);
            if (lane >= d) x += y;
        }
        if (i < nb) bsum[i] = carry + x - v;  // exclusive block base
        carry += __shfl(x, 63, 64);
    }
    if (lane == 0) offs[n] = carry;
}

// phase 3: local exclusive scan + block base -> offs, cursor
__global__ __launch_bounds__(256) void k_scan3(
    const int* __restrict__ deg, const int* __restrict__ bsum,
    int* __restrict__ offs, int* __restrict__ cursor, int n)
{
    const int t = threadIdx.x;
    const int lane = t & 63, wid = t >> 6;
    const int i0 = blockIdx.x * 1024 + t * 4;
    const int d0 = (i0     < n) ? deg[i0]     : 0;
    const int d1 = (i0 + 1 < n) ? deg[i0 + 1] : 0;
    const int d2 = (i0 + 2 < n) ? deg[i0 + 2] : 0;
    const int d3 = (i0 + 3 < n) ? deg[i0 + 3] : 0;
    const int v = d0 + d1 + d2 + d3;
    int x = v;
#pragma unroll
    for (int d = 1; d < 64; d <<= 1) {
        const int y = __shfl_up(x, d, 64);
        if (lane >= d) x += y;
    }
    __shared__ int ws[4];
    if (lane == 63) ws[wid] = x;
    __syncthreads();
    int wbase = 0;
    for (int q = 0; q < wid; q++) wbase += ws[q];
    int excl = bsum[blockIdx.x] + wbase + (x - v);
    if (i0     < n) { offs[i0]     = excl; cursor[i0]     = excl; }
    excl += d0;
    if (i0 + 1 < n) { offs[i0 + 1] = excl; cursor[i0 + 1] = excl; }
    excl += d1;
    if (i0 + 2 < n) { offs[i0 + 2] = excl; cursor[i0 + 2] = excl; }
    excl += d2;
    if (i0 + 3 < n) { offs[i0 + 3] = excl; cursor[i0 + 3] = excl; }
}

// se[p] = (src, edge_id): single 8B scattered store
__global__ __launch_bounds__(256) void k_scatter(
    const int* __restrict__ src, const int* __restrict__ dst,
    int* __restrict__ cursor, int2* __restrict__ se, int E)
{
    const int e = blockIdx.x * 256 + threadIdx.x;
    if (e >= E) return;
    const int p = atomicAdd(&cursor[dst[e]], 1);
    se[p] = make_int2(src[e], e);
}

// ======= layer-1 node projections (fp16 outputs) + fp16 copy of nf ==========
// 32 nodes/block; 8 nodes/wave -> halves per-block weight re-reads.
__global__ __launch_bounds__(256) void k_nodeproj1(
    const float* __restrict__ nf, const float* __restrict__ Wni,
    const float* __restrict__ Wnj,
    _Float16* __restrict__ fni16, _Float16* __restrict__ fnj16,
    _Float16* __restrict__ nf16, int n)
{
    __shared__ float s[128][36];
    const int t = threadIdx.x;
    const int node0 = blockIdx.x * NPB1;
#pragma unroll
    for (int i = 0; i < 4; i++) {
        const int idx = i * 256 + t;      // 0..1023
        const int nl = idx >> 5;          // 0..31
        const int k4 = (idx & 31) * 4;    // 0..124
        const int node = node0 + nl;
        vf4 v = {0.f, 0.f, 0.f, 0.f};
        if (node < n) v = *(const vf4*)(nf + (size_t)node * 128 + k4);
        s[k4][nl] = v.x; s[k4 + 1][nl] = v.y;
        s[k4 + 2][nl] = v.z; s[k4 + 3][nl] = v.w;
        if (node < n) {
            vh4 o;
            o[0] = (_Float16)v.x; o[1] = (_Float16)v.y;
            o[2] = (_Float16)v.z; o[3] = (_Float16)v.w;
            *(vh4*)(nf16 + (size_t)node * 128 + k4) = o;
        }
    }
    __syncthreads();
    const int lane = t & 63;
    const int w8 = (t >> 6) * 8;
    float ai[8] = {0, 0, 0, 0, 0, 0, 0, 0}, aj[8] = {0, 0, 0, 0, 0, 0, 0, 0};
#pragma unroll 4
    for (int k = 0; k < 128; k++) {
        const float wi = Wni[(size_t)k * 64 + lane];
        const float wj = Wnj[(size_t)k * 64 + lane];
        const float4 sv0 = *(const float4*)&s[k][w8];
        const float4 sv1 = *(const float4*)&s[k][w8 + 4];
        const float sl[8] = {sv0.x, sv0.y, sv0.z, sv0.w,
                             sv1.x, sv1.y, sv1.z, sv1.w};
#pragma unroll
        for (int nn = 0; nn < 8; nn++) {
            ai[nn] = fmaf(wi, sl[nn], ai[nn]);
            aj[nn] = fmaf(wj, sl[nn], aj[nn]);
        }
    }
#pragma unroll
    for (int nn = 0; nn < 8; nn++) {
        const int node = node0 + w8 + nn;
        if (node < n) {
            fni16[(size_t)node * 64 + lane] = (_Float16)ai[nn];
            fnj16[(size_t)node * 64 + lane] = (_Float16)aj[nn];
        }
    }
}

// ====== layer-1 fused: edge features + softmax + nf-space aggregate =========
// depth-1 software pipeline + packed (g,t) DPP row-sum.
__global__ __launch_bounds__(256, 4) void k_l1(
    const int* __restrict__ offs, const int2* __restrict__ se,
    const _Float16* __restrict__ ef16,
    const _Float16* __restrict__ nf16, const _Float16* __restrict__ fni16,
    const _Float16* __restrict__ fnj16, const float* __restrict__ Wfij,
    const float* __restrict__ bedge, const float* __restrict__ attn,
    const float* __restrict__ Wfij2,
    _Float16* __restrict__ g2s, _Float16* __restrict__ zbuf, int n)
{
    const int lane = threadIdx.x & 63;
    const int node = __builtin_amdgcn_readfirstlane(blockIdx.x * 4 + (threadIdx.x >> 6));
    if (node >= n) return;
    const int beg = offs[node], end = offs[node + 1];
    const float fjb = (float)fnj16[(size_t)node * 64 + lane] + bedge[lane];
    const float at = attn[lane];
    const float w2fq = 0.25f * Wfij2[(lane & 15) * 4 + (lane >> 4)];
    // packed fp16 weight pairs: wf[j] = (Wfij[2j][lane], Wfij[2j+1][lane])
    vh2 wf[16];
#pragma unroll
    for (int j = 0; j < 16; j++) {
        vh2 p;
        p.x = (_Float16)Wfij[(2 * j) * 64 + lane];
        p.y = (_Float16)Wfij[(2 * j + 1) * 64 + lane];
        wf[j] = p;
    }
#pragma unroll
    for (int j = 0; j < 16; j++) asm volatile("" : "+v"(wf[j]));

    float s0 = 0.f, s1 = 0.f, s2 = 0.f, s3 = 0.f;
    vf2 z0 = {0.f, 0.f}, z1 = {0.f, 0.f}, z2 = {0.f, 0.f}, z3 = {0.f, 0.f};

#define PAIR(u, j) (vh2){(u)[2 * (j)], (u)[2 * (j) + 1]}
    for (int base = beg; base < end; base += 64) {
        const int rem = end - base;
        const int cnt = (rem < 64) ? rem : 64;
        const int idx = base + ((lane < cnt) ? lane : (cnt - 1));
        const int2 sev = se[idx];
        const int spv = sev.x, edv = sev.y;
        // prologue: load edge 0
        {
            const int sp0 = __builtin_amdgcn_readlane(spv, 0);
            const int ed0 = __builtin_amdgcn_readlane(edv, 0);
            const vh8* __restrict__ er0 =
                (const vh8*)(ef16 + ((size_t)(unsigned)ed0 << 5));
            vh8 u0 = __builtin_nontemporal_load(er0 + 0);
            vh8 u1 = __builtin_nontemporal_load(er0 + 1);
            vh8 u2 = __builtin_nontemporal_load(er0 + 2);
            vh8 u3 = __builtin_nontemporal_load(er0 + 3);
            float fniv = (float)fni16[(size_t)(unsigned)sp0 * 64 + lane];
            vh2 nvh = *(const vh2*)(nf16 + (size_t)(unsigned)sp0 * 128 + lane * 2);
            for (int it = 0; it < cnt; ++it) {
                // issue next edge's gathers (prefetch)
                const int itn = (it + 1 < cnt) ? (it + 1) : it;
                const int spn = __builtin_amdgcn_readlane(spv, itn);
                const int edn = __builtin_amdgcn_readlane(edv, itn);
                const vh8* __restrict__ ern =
                    (const vh8*)(ef16 + ((size_t)(unsigned)edn << 5));
                const vh8 w0 = __builtin_nontemporal_load(ern + 0);
                const vh8 w1 = __builtin_nontemporal_load(ern + 1);
                const vh8 w2 = __builtin_nontemporal_load(ern + 2);
                const vh8 w3 = __builtin_nontemporal_load(ern + 3);
                const float fnin = (float)fni16[(size_t)(unsigned)spn * 64 + lane];
                const vh2 nvhn = *(const vh2*)(nf16 + (size_t)(unsigned)spn * 128 + lane * 2);
                // ---- compute current edge (pure-register)
                float f0 = fniv + fjb;
                f0 = __builtin_amdgcn_fdot2(PAIR(u0, 0), wf[0],  f0, false);
                f0 = __builtin_amdgcn_fdot2(PAIR(u0, 1), wf[1],  f0, false);
                f0 = __builtin_amdgcn_fdot2(PAIR(u0, 2), wf[2],  f0, false);
                f0 = __builtin_amdgcn_fdot2(PAIR(u0, 3), wf[3],  f0, false);
                float f1 = __builtin_amdgcn_fdot2(PAIR(u1, 0), wf[4], 0.f, false);
                f1 = __builtin_amdgcn_fdot2(PAIR(u1, 1), wf[5],  f1, false);
                f1 = __builtin_amdgcn_fdot2(PAIR(u1, 2), wf[6],  f1, false);
                f1 = __builtin_amdgcn_fdot2(PAIR(u1, 3), wf[7],  f1, false);
                float f2 = __builtin_amdgcn_fdot2(PAIR(u2, 0), wf[8], 0.f, false);
                f2 = __builtin_amdgcn_fdot2(PAIR(u2, 1), wf[9],  f2, false);
                f2 = __builtin_amdgcn_fdot2(PAIR(u2, 2), wf[10], f2, false);
                f2 = __builtin_amdgcn_fdot2(PAIR(u2, 3), wf[11], f2, false);
                float f3 = __builtin_amdgcn_fdot2(PAIR(u3, 0), wf[12], 0.f, false);
                f3 = __builtin_amdgcn_fdot2(PAIR(u3, 1), wf[13], f3, false);
                f3 = __builtin_amdgcn_fdot2(PAIR(u3, 2), wf[14], f3, false);
                f3 = __builtin_amdgcn_fdot2(PAIR(u3, 3), wf[15], f3, false);
                const float f = (f0 + f1) + (f2 + f3);
                const float fl = (f > 0.f) ? f : SLOPE * f;
                float r = fmaxf(fl, 0.f);
                r += __shfl_xor(r, 16, 64);
                r += __shfl_xor(r, 32, 64);
                // packed (g, t) row-sum: one DPP chain for both
                vh2 pk;
                pk.x = (_Float16)(r * w2fq);
                pk.y = (_Float16)(fl * at);
                pk = dpp_sum16_pk(pk);
                if ((lane & 15) == 15)
                    g2s[(size_t)(base + it) * 4 + (lane >> 4)] = pk.x;
                const float ce = __expf((float)pk.y);
                const float c0 = bcast_lane(ce, 15);
                const float c1 = bcast_lane(ce, 31);
                const float c2 = bcast_lane(ce, 47);
                const float c3 = bcast_lane(ce, 63);
                const float nvx = (float)nvh.x, nvy = (float)nvh.y;
                s0 += c0; s1 += c1; s2 += c2; s3 += c3;
                z0.x = fmaf(c0, nvx, z0.x); z0.y = fmaf(c0, nvy, z0.y);
                z1.x = fmaf(c1, nvx, z1.x); z1.y = fmaf(c1, nvy, z1.y);
                z2.x = fmaf(c2, nvx, z2.x); z2.y = fmaf(c2, nvy, z2.y);
                z3.x = fmaf(c3, nvx, z3.x); z3.y = fmaf(c3, nvy, z3.y);
                // rotate pipeline registers
                u0 = w0; u1 = w1; u2 = w2; u3 = w3;
                fniv = fnin; nvh = nvhn;
            }
        }
    }
#undef PAIR
    const float i0 = (s0 > 0.f) ? 1.f / s0 : 0.f;
    const float i1 = (s1 > 0.f) ? 1.f / s1 : 0.f;
    const float i2 = (s2 > 0.f) ? 1.f / s2 : 0.f;
    const float i3 = (s3 > 0.f) ? 1.f / s3 : 0.f;
    _Float16* zb = zbuf + (size_t)node * 512;
    vh2 o;
    o.x = (_Float16)(z0.x * i0); o.y = (_Float16)(z0.y * i0);
    *(vh2*)(zb + 0   + lane * 2) = o;
    o.x = (_Float16)(z1.x * i1); o.y = (_Float16)(z1.y * i1);
    *(vh2*)(zb + 128 + lane * 2) = o;
    o.x = (_Float16)(z2.x * i2); o.y = (_Float16)(z2.y * i2);
    *(vh2*)(zb + 256 + lane * 2) = o;
    o.x = (_Float16)(z3.x * i3); o.y = (_Float16)(z3.y * i3);
    *(vh2*)(zb + 384 + lane * 2) = o;
}

// ====== z-space -> hbuf projection via packed fp16 dot2 =====================
// hbuf = 0.25*sum_h relu(z_h@Wnode_h + b_h); LDS holds z as vh2 k-pairs.
__global__ __launch_bounds__(256) void k_zproj(
    const _Float16* __restrict__ zbuf, const int* __restrict__ offs,
    const float* __restrict__ Wnode, const float* __restrict__ bnode,
    _Float16* __restrict__ hbuf16, int n)
{
    __shared__ vh2 s2[256][20];  // [k-pair][node], rows 80B (16B-aligned)
    const int t = threadIdx.x;
    const int node0 = blockIdx.x * NPB;
#pragma unroll
    for (int i = 0; i < 8; i++) {
        const int idx = i * 256 + t;        // 0..2047
        const int nl = idx >> 7;            // 0..15
        const int q4 = idx & 127;           // 4-half chunk 0..127
        const int node = node0 + nl;
        vh4 v = {0.f, 0.f, 0.f, 0.f};
        if (node < n) v = *(const vh4*)(zbuf + (size_t)node * 512 + q4 * 4);
        vh2 p0; p0.x = v[0]; p0.y = v[1];
        vh2 p1; p1.x = v[2]; p1.y = v[3];
        s2[q4 * 2][nl]     = p0;
        s2[q4 * 2 + 1][nl] = p1;
    }
    __syncthreads();
    const int lane = t & 63;
    const int w4 = (t >> 6) * 4;
    bool zf[4];
    float hb[4] = {0, 0, 0, 0};
#pragma unroll
    for (int nn = 0; nn < 4; nn++) {
        const int node = node0 + w4 + nn;
        zf[nn] = (node < n) && (offs[node] < offs[node + 1]);
    }
#pragma unroll
    for (int h = 0; h < 4; h++) {
        float acc[4];
        const float bv = bnode[h * 64 + lane];
#pragma unroll
        for (int nn = 0; nn < 4; nn++) acc[nn] = zf[nn] ? bv : 0.f;
#pragma unroll 2
        for (int kp = 0; kp < 64; kp++) {
            const float w0 = Wnode[(size_t)(2 * kp) * 256 + h * 64 + lane];
            const float w1 = Wnode[(size_t)(2 * kp + 1) * 256 + h * 64 + lane];
            vh2 wp; wp.x = (_Float16)w0; wp.y = (_Float16)w1;
            // 4 node-pairs, one 16B broadcast LDS read
            const vh8 zv = *(const vh8*)&s2[h * 64 + kp][w4];
            vh2 a;
            a.x = zv[0]; a.y = zv[1];
            acc[0] = __builtin_amdgcn_fdot2(a, wp, acc[0], false);
            a.x = zv[2]; a.y = zv[3];
            acc[1] = __builtin_amdgcn_fdot2(a, wp, acc[1], false);
            a.x = zv[4]; a.y = zv[5];
            acc[2] = __builtin_amdgcn_fdot2(a, wp, acc[2], false);
            a.x = zv[6]; a.y = zv[7];
            acc[3] = __builtin_amdgcn_fdot2(a, wp, acc[3], false);
        }
#pragma unroll
        for (int nn = 0; nn < 4; nn++) hb[nn] += fmaxf(acc[nn], 0.f);
    }
#pragma unroll
    for (int nn = 0; nn < 4; nn++) {
        const int node = node0 + w4 + nn;
        if (node < n) hbuf16[(size_t)node * 64 + lane] = (_Float16)(0.25f * hb[nn]);
    }
}

// ======================= layer-2 node projections ===========================
__global__ __launch_bounds__(256) void k_nodeproj2(
    const _Float16* __restrict__ hbuf16, const float* __restrict__ Wni,
    const float* __restrict__ Wnj, const float* __restrict__ Wnode,
    const float* __restrict__ bnode,
    float* __restrict__ fni2, float* __restrict__ fnj2,
    _Float16* __restrict__ ft2h, int n)
{
    __shared__ float sh[4][64];
    const int lane = threadIdx.x & 63, w = threadIdx.x >> 6;
    const int node = blockIdx.x * 4 + w;
    const int nc = (node < n) ? node : (n - 1);
    const float v = (float)hbuf16[(size_t)nc * 64 + lane];
    sh[w][lane] = v;
    __syncthreads();
    float acc = bnode[lane];
#pragma unroll 4
    for (int k = 0; k < 64; k++) acc = fmaf(sh[w][k], Wnode[k * 64 + lane], acc);
    float pi[4], pj[4];
#pragma unroll
    for (int h = 0; h < 4; h++) { pi[h] = v * Wni[lane * 4 + h]; pj[h] = v * Wnj[lane * 4 + h]; }
#pragma unroll
    for (int mk = 1; mk < 64; mk <<= 1) {
#pragma unroll
        for (int h = 0; h < 4; h++) {
            pi[h] += __shfl_xor(pi[h], mk, 64);
            pj[h] += __shfl_xor(pj[h], mk, 64);
        }
    }
    if (node < n) {
        ft2h[(size_t)node * 64 + lane] = (_Float16)acc;
        if (lane == 0) {
            *(float4*)(fni2 + (size_t)node * 4) = make_float4(pi[0], pi[1], pi[2], pi[3]);
            *(float4*)(fnj2 + (size_t)node * 4) = make_float4(pj[0], pj[1], pj[2], pj[3]);
        }
    }
}

// ====== layer-2 fused: edge logits + softmax + message passing ==============
// depth-1 software pipeline (R17 proven best).
__global__ __launch_bounds__(256) void k_l2(
    const int* __restrict__ offs, const int2* __restrict__ se,
    const _Float16* __restrict__ g2s, const float* __restrict__ fni2,
    const float* __restrict__ fnj2, const _Float16* __restrict__ ft2h,
    const float* __restrict__ bedge2, const float* __restrict__ attn2,
    float* __restrict__ out, int n)
{
    const int lane = threadIdx.x & 63;
    const int node = __builtin_amdgcn_readfirstlane(blockIdx.x * 4 + (threadIdx.x >> 6));
    if (node >= n) return;
    const int beg = offs[node], end = offs[node + 1];
    const int h = lane >> 4;
    const float base_ = fnj2[(size_t)node * 4 + h] + bedge2[h];
    const float at = attn2[h];
    float s = 0.f, acc = 0.f;
    for (int base = beg; base < end; base += 64) {
        const int rem = end - base;
        const int cnt = (rem < 64) ? rem : 64;
        const int idx = base + ((lane < cnt) ? lane : (cnt - 1));
        const int spv = se[idx].x;
        // prologue: edge 0
        const int sp0 = __builtin_amdgcn_readlane(spv, 0);
        vh4 gq = *(const vh4*)(g2s + (size_t)base * 4);
        float4 fq = *(const float4*)(fni2 + (size_t)(unsigned)sp0 * 4);
        float ftv = (float)ft2h[(size_t)(unsigned)sp0 * 64 + lane];
        for (int it = 0; it < cnt; ++it) {
            const int itn = (it + 1 < cnt) ? (it + 1) : it;
            const int spn = __builtin_amdgcn_readlane(spv, itn);
            const vh4 gqn = *(const vh4*)(g2s + (size_t)(base + itn) * 4);
            const float4 fqn = *(const float4*)(fni2 + (size_t)(unsigned)spn * 4);
            const float ftvn = (float)ft2h[(size_t)(unsigned)spn * 64 + lane];
            // compute current
            const float gh = (float)((h == 0) ? gq.x : (h == 1) ? gq.y : (h == 2) ? gq.z : gq.w);
            const float fh = (h == 0) ? fq.x : (h == 1) ? fq.y : (h == 2) ? fq.z : fq.w;
            const float f = base_ + fh + gh;
            const float fl = (f > 0.f) ? f : SLOPE * f;
            const float c = __expf(fl * at);
            s += c;
            acc = fmaf(c, ftv, acc);
            // rotate
            gq = gqn; fq = fqn; ftv = ftvn;
        }
    }
    out[(size_t)node * 64 + lane] = (s > 0.f) ? acc / s : 0.f;
}

extern "C" void kernel_launch(void* const* d_in, const int* in_sizes, int n_in,
                              void* d_out, int out_size, void* d_ws, size_t ws_size,
                              hipStream_t stream)
{
    const float* nfeat  = (const float*)d_in[0];
    const float* efeat  = (const float*)d_in[1];
    const int*   src    = (const int*)d_in[2];
    const int*   dst    = (const int*)d_in[3];
    const float* W1ni   = (const float*)d_in[4];
    const float* W1fij  = (const float*)d_in[5];
    const float* W1nj   = (const float*)d_in[6];
    const float* b1e    = (const float*)d_in[7];
    const float* W1node = (const float*)d_in[8];
    const float* b1n    = (const float*)d_in[9];
    const float* attn1  = (const float*)d_in[10];
    const float* W2ni   = (const float*)d_in[11];
    const float* W2fij  = (const float*)d_in[12];
    const float* W2nj   = (const float*)d_in[13];
    const float* b2e    = (const float*)d_in[14];
    const float* W2node = (const float*)d_in[15];
    const float* b2n    = (const float*)d_in[16];
    const float* attn2  = (const float*)d_in[17];
    const int n = in_sizes[0] / 128;
    const int E = in_sizes[2];
    float* out = (float*)d_out;

    char* w = (char*)d_ws;
    auto alloc = [&](size_t bytes) {
        char* p = w; w += (bytes + 255) & ~(size_t)255; return p;
    };
    _Float16* ef16  = (_Float16*)alloc((size_t)E * 32 * 2);
    _Float16* zbuf  = (_Float16*)alloc((size_t)n * 512 * 2);
    _Float16* g2s   = (_Float16*)alloc((size_t)E * 4 * 2);
    _Float16* fni16 = (_Float16*)alloc((size_t)n * 64 * 2);
    _Float16* fnj16 = (_Float16*)alloc((size_t)n * 64 * 2);
    _Float16* nf16  = (_Float16*)alloc((size_t)n * 128 * 2);
    _Float16* ft2h  = (_Float16*)alloc((size_t)n * 64 * 2);
    _Float16* hbuf16= (_Float16*)alloc((size_t)n * 64 * 2);
    int*      deg   = (int*)alloc((size_t)n * 4);
    int*      offs  = (int*)alloc((size_t)(n + 1) * 4);
    int*      curs  = (int*)alloc((size_t)n * 4);
    int2*     se    = (int2*)alloc((size_t)E * 8);
    float*    fni2  = (float*)alloc((size_t)n * 4 * 4);
    float*    fnj2  = (float*)alloc((size_t)n * 4 * 4);
    const int nb = (n + 1023) / 1024;
    int*      bsum  = (int*)alloc((size_t)nb * 4);

    // ---- CSR build (parallel scan) + ef fp16 conversion
    hipMemsetAsync(deg, 0, (size_t)n * 4, stream);
    const int cvtBlocks = (int)(((size_t)E * 4 + 255) / 256);
    k_deg_cvt<<<cvtBlocks, 256, 0, stream>>>(dst, deg, efeat, ef16, E);
    k_scan1<<<nb, 256, 0, stream>>>(deg, bsum, n);
    k_scan2<<<1, 64, 0, stream>>>(bsum, offs, nb, n);
    k_scan3<<<nb, 256, 0, stream>>>(deg, bsum, offs, curs, n);
    k_scatter<<<(E + 255) / 256, 256, 0, stream>>>(src, dst, curs, se, E);

    // ---- layer 1
    k_nodeproj1<<<(n + NPB1 - 1) / NPB1, 256, 0, stream>>>(
        nfeat, W1ni, W1nj, fni16, fnj16, nf16, n);
    k_l1<<<(n + 3) / 4, 256, 0, stream>>>(offs, se, ef16, nf16,
                                          fni16, fnj16, W1fij, b1e, attn1,
                                          W2fij, g2s, zbuf, n);
    k_zproj<<<(n + NPB - 1) / NPB, 256, 0, stream>>>(zbuf, offs, W1node, b1n,
                                                     hbuf16, n);
    // ---- layer 2
    k_nodeproj2<<<(n + 3) / 4, 256, 0, stream>>>(hbuf16, W2ni, W2nj, W2node, b2n,
                                                 fni2, fnj2, ft2h, n);
    k_l2<<<(n + 3) / 4, 256, 0, stream>>>(offs, se, g2s, fni2, fnj2, ft2h,
                                          b2e, attn2, out, n);
}